// Round 4
// baseline (222.694 us; speedup 1.0000x reference)
//
#include <hip/hip_runtime.h>

// Problem dims (fixed by reference): B=8, L=4096, K=32, C=64, KC=2048
#define B_DIM 8
#define L_DIM 4096
#define KC 2048              // K*C, contiguous innermost span per (b,l)
#define LCB  16              // l-rows per bcast block -> 2048 blocks
#define PT   512             // partial_k threads: one float4 column each
#define DEPTH 8              // rows per load-batch: 16 loads in flight

// ---------------------------------------------------------------------------
// Stage 1: per-(b,segment) private partial sums/counts. No atomics.
// Thread t owns float4 column t. Per DEPTH-row chunk we issue all 16 loads
// (interleaved x/mask) into statically-indexed register arrays BEFORE any
// consumption -> up to 16 loads (256 B/lane) in flight per wave.
// No __launch_bounds__ VGPR squeeze: let the compiler take ~128 VGPRs.
// ---------------------------------------------------------------------------
__global__ void partial_k(const float* __restrict__ x,
                          const int* __restrict__ mask,
                          float* __restrict__ psum,
                          float* __restrict__ pcnt,
                          int nseg, int lrows) {
    const int b   = blockIdx.x / nseg;
    const int seg = blockIdx.x % nseg;
    const int t   = threadIdx.x;

    const long base = ((long)b * L_DIM + (long)seg * lrows) * KC + t * 4;

    float4 s = make_float4(0.f, 0.f, 0.f, 0.f);
    float4 c = make_float4(0.f, 0.f, 0.f, 0.f);

    for (int l0 = 0; l0 < lrows; l0 += DEPTH) {
        float4 xv[DEPTH];
        int4   mv[DEPTH];
        const long rb = base + (long)l0 * KC;
        // issue all loads first, interleaved, statically indexed
        #pragma unroll
        for (int j = 0; j < DEPTH; ++j) {
            xv[j] = *(const float4*)(x    + rb + (long)j * KC);
            mv[j] = *(const int4*)  (mask + rb + (long)j * KC);
        }
        // consume in issue order (waitcnt stays high-water)
        #pragma unroll
        for (int j = 0; j < DEPTH; ++j) {
            float m0 = (float)mv[j].x, m1 = (float)mv[j].y;
            float m2 = (float)mv[j].z, m3 = (float)mv[j].w;
            s.x = fmaf(xv[j].x, m0, s.x);  c.x += m0;
            s.y = fmaf(xv[j].y, m1, s.y);  c.y += m1;
            s.z = fmaf(xv[j].z, m2, s.z);  c.z += m2;
            s.w = fmaf(xv[j].w, m3, s.w);  c.w += m3;
        }
    }

    const long po = ((long)b * nseg + seg) * KC + t * 4;
    *(float4*)(&psum[po]) = s;
    *(float4*)(&pcnt[po]) = c;
}

// ---------------------------------------------------------------------------
// Stage 2: fold nseg partials per (b,j), finalize mean. B*KC = 16384 threads.
// ---------------------------------------------------------------------------
__global__ __launch_bounds__(256) void mean_k(const float* __restrict__ psum,
                                              const float* __restrict__ pcnt,
                                              float* __restrict__ mean,
                                              int nseg) {
    const int i = blockIdx.x * 256 + threadIdx.x;   // 0 .. B*KC-1
    const int b = i / KC;
    const int j = i % KC;

    float s = 0.f, c = 0.f;
    #pragma unroll 4
    for (int seg = 0; seg < nseg; ++seg) {
        const long o = ((long)b * nseg + seg) * KC + j;
        s += psum[o];
        c += pcnt[o];
    }
    mean[i] = (c > 0.f) ? (s / c) : 0.f;
}

// ---------------------------------------------------------------------------
// Stage 3: broadcast mean[b,:,:] to all L rows. mean is 64 KB -> L2-resident;
// read the thread's float4 once and stream stores (~7 TB/s measured).
// ---------------------------------------------------------------------------
__global__ __launch_bounds__(PT) void bcast_k(const float* __restrict__ mean,
                                              float* __restrict__ out) {
    const int blocks_per_b = L_DIM / LCB;           // 256
    const int b    = blockIdx.x / blocks_per_b;
    const int lseg = blockIdx.x % blocks_per_b;
    const int t    = threadIdx.x;

    const float4 v = *(const float4*)(&mean[(long)b * KC + t * 4]);

    const long base = ((long)b * L_DIM + (long)lseg * LCB) * KC + t * 4;
    #pragma unroll
    for (int l = 0; l < LCB; ++l)
        *(float4*)(out + base + (long)l * KC) = v;
}

extern "C" void kernel_launch(void* const* d_in, const int* in_sizes, int n_in,
                              void* d_out, int out_size, void* d_ws, size_t ws_size,
                              hipStream_t stream) {
    const float* x    = (const float*)d_in[0];
    const int*   mask = (const int*)d_in[1];
    float*       out  = (float*)d_out;
    float*       ws   = (float*)d_ws;

    // Largest nseg whose partials fit in ws: (2*B*nseg*KC + B*KC)*4 bytes.
    // nseg=256 -> 33.6 MB (fits; ws is ~800 MB). lrows stays a multiple of 8.
    int nseg = 256;
    while (nseg > 8 &&
           (size_t)(2ul * B_DIM * nseg * KC + B_DIM * KC) * 4ul > ws_size)
        nseg >>= 1;
    const int lrows = L_DIM / nseg;

    float* psum = ws;
    float* pcnt = ws + (long)B_DIM * nseg * KC;
    float* mean = ws + 2l * B_DIM * nseg * KC;

    // 1) private partial sums/counts (no atomics), deep-MLP loads
    partial_k<<<B_DIM * nseg, PT, 0, stream>>>(x, mask, psum, pcnt,
                                               nseg, lrows);

    // 2) fold partials, finalize mean
    mean_k<<<(B_DIM * KC) / 256, 256, 0, stream>>>(psum, pcnt, mean, nseg);

    // 3) broadcast to [B, L, K, C]
    bcast_k<<<B_DIM * (L_DIM / LCB), PT, 0, stream>>>(mean, out);
}

// Round 5
// 217.294 us; speedup vs baseline: 1.0248x; 1.0248x over previous
//
#include <hip/hip_runtime.h>

// Problem dims (fixed by reference): B=8, L=4096, K=32, C=64, KC=2048
#define B_DIM 8
#define L_DIM 4096
#define KC 2048              // K*C, contiguous innermost span per (b,l)
#define LCB  16              // l-rows per bcast block -> 2048 blocks
#define PT   512             // threads: one float4 column each

typedef float f4 __attribute__((ext_vector_type(4)));
typedef int   i4 __attribute__((ext_vector_type(4)));

// Inline-asm load: compiler cannot collapse the ring or early-wait it.
#define GLD_F4(dst, p) asm volatile("global_load_dwordx4 %0, %1, off" : "=v"(dst) : "v"(p))
#define GLD_I4(dst, p) asm volatile("global_load_dwordx4 %0, %1, off" : "=v"(dst) : "v"(p))
#define WAITV(n) asm volatile("s_waitcnt vmcnt(" #n ")" ::: "memory")
#define SB() __builtin_amdgcn_sched_barrier(0)

// Consume pair J: mask->float, 4 FMA into s, 4 adds into c.
#define CONS(J) do {                                        \
    float m0 = (float)mv##J[0], m1 = (float)mv##J[1];       \
    float m2 = (float)mv##J[2], m3 = (float)mv##J[3];       \
    s[0] = fmaf(xv##J[0], m0, s[0]);  c[0] += m0;           \
    s[1] = fmaf(xv##J[1], m1, s[1]);  c[1] += m1;           \
    s[2] = fmaf(xv##J[2], m2, s[2]);  c[2] += m2;           \
    s[3] = fmaf(xv##J[3], m3, s[3]);  c[3] += m3;           \
} while (0)

// Steady-state step: wait for oldest pair (14 = 16 outstanding - 2),
// consume it, immediately re-issue that slot for the next 8-row chunk.
#define STEP(J, XN, MN) do {                                \
    WAITV(14); SB(); CONS(J);                               \
    GLD_F4(xv##J, (XN) + (long)(J) * KC);                   \
    GLD_I4(mv##J, (MN) + (long)(J) * KC);                   \
} while (0)

// ---------------------------------------------------------------------------
// Stage 1: per-(b,segment) private partial sums/counts. No atomics.
// Thread t owns float4 column t. Depth-8 pair ring (16 loads / 256 B per lane
// in flight), counted vmcnt per AITER pattern — never drained in the loop.
// lrows must be a multiple of 8 and >= 8 (guaranteed by launcher).
// ---------------------------------------------------------------------------
__global__ __launch_bounds__(PT) void partial_k(const float* __restrict__ x,
                                                const int* __restrict__ mask,
                                                float* __restrict__ psum,
                                                float* __restrict__ pcnt,
                                                int nseg, int lrows) {
    const int b   = blockIdx.x / nseg;
    const int seg = blockIdx.x % nseg;
    const int t   = threadIdx.x;

    const long base = ((long)b * L_DIM + (long)seg * lrows) * KC + t * 4;
    const float* xp = x + base;
    const int*   mp = mask + base;

    f4 s = {0.f, 0.f, 0.f, 0.f};
    f4 c = {0.f, 0.f, 0.f, 0.f};

    f4 xv0, xv1, xv2, xv3, xv4, xv5, xv6, xv7;
    i4 mv0, mv1, mv2, mv3, mv4, mv5, mv6, mv7;

    // Prologue: issue pairs for rows 0..7 (16 loads outstanding).
    GLD_F4(xv0, xp + 0l * KC);  GLD_I4(mv0, mp + 0l * KC);
    GLD_F4(xv1, xp + 1l * KC);  GLD_I4(mv1, mp + 1l * KC);
    GLD_F4(xv2, xp + 2l * KC);  GLD_I4(mv2, mp + 2l * KC);
    GLD_F4(xv3, xp + 3l * KC);  GLD_I4(mv3, mp + 3l * KC);
    GLD_F4(xv4, xp + 4l * KC);  GLD_I4(mv4, mp + 4l * KC);
    GLD_F4(xv5, xp + 5l * KC);  GLD_I4(mv5, mp + 5l * KC);
    GLD_F4(xv6, xp + 6l * KC);  GLD_I4(mv6, mp + 6l * KC);
    GLD_F4(xv7, xp + 7l * KC);  GLD_I4(mv7, mp + 7l * KC);

    // Main: chunks 0..NT-2, each consumes its 8 pairs and issues the next chunk.
    for (int l0 = 0; l0 < lrows - 8; l0 += 8) {
        const float* xn = xp + (long)(l0 + 8) * KC;
        const int*   mn = mp + (long)(l0 + 8) * KC;
        STEP(0, xn, mn);
        STEP(1, xn, mn);
        STEP(2, xn, mn);
        STEP(3, xn, mn);
        STEP(4, xn, mn);
        STEP(5, xn, mn);
        STEP(6, xn, mn);
        STEP(7, xn, mn);
    }

    // Epilogue: drain last chunk with decreasing counted waits.
    WAITV(14); SB(); CONS(0);
    WAITV(12); SB(); CONS(1);
    WAITV(10); SB(); CONS(2);
    WAITV(8);  SB(); CONS(3);
    WAITV(6);  SB(); CONS(4);
    WAITV(4);  SB(); CONS(5);
    WAITV(2);  SB(); CONS(6);
    WAITV(0);  SB(); CONS(7);

    const long po = ((long)b * nseg + seg) * KC + t * 4;
    *(f4*)(&psum[po]) = s;
    *(f4*)(&pcnt[po]) = c;
}

// ---------------------------------------------------------------------------
// Stage 2: fold nseg partials per (b,j), finalize mean. B*KC = 16384 threads.
// ---------------------------------------------------------------------------
__global__ __launch_bounds__(256) void mean_k(const float* __restrict__ psum,
                                              const float* __restrict__ pcnt,
                                              float* __restrict__ mean,
                                              int nseg) {
    const int i = blockIdx.x * 256 + threadIdx.x;   // 0 .. B*KC-1
    const int b = i / KC;
    const int j = i % KC;

    float s = 0.f, c = 0.f;
    #pragma unroll 4
    for (int seg = 0; seg < nseg; ++seg) {
        const long o = ((long)b * nseg + seg) * KC + j;
        s += psum[o];
        c += pcnt[o];
    }
    mean[i] = (c > 0.f) ? (s / c) : 0.f;
}

// ---------------------------------------------------------------------------
// Stage 3: broadcast mean[b,:,:] to all L rows. mean is 64 KB -> L2-resident;
// read the thread's float4 once and stream stores.
// ---------------------------------------------------------------------------
__global__ __launch_bounds__(PT) void bcast_k(const float* __restrict__ mean,
                                              float* __restrict__ out) {
    const int blocks_per_b = L_DIM / LCB;           // 256
    const int b    = blockIdx.x / blocks_per_b;
    const int lseg = blockIdx.x % blocks_per_b;
    const int t    = threadIdx.x;

    const float4 v = *(const float4*)(&mean[(long)b * KC + t * 4]);

    const long base = ((long)b * L_DIM + (long)lseg * LCB) * KC + t * 4;
    #pragma unroll
    for (int l = 0; l < LCB; ++l)
        *(float4*)(out + base + (long)l * KC) = v;
}

extern "C" void kernel_launch(void* const* d_in, const int* in_sizes, int n_in,
                              void* d_out, int out_size, void* d_ws, size_t ws_size,
                              hipStream_t stream) {
    const float* x    = (const float*)d_in[0];
    const int*   mask = (const int*)d_in[1];
    float*       out  = (float*)d_out;
    float*       ws   = (float*)d_ws;

    // Largest nseg whose partials fit in ws: (2*B*nseg*KC + B*KC)*4 bytes.
    // Keep lrows (=L/nseg) a multiple of 8 and >= 8: nseg <= 512, pow2.
    int nseg = 256;
    while (nseg > 8 &&
           (size_t)(2ul * B_DIM * nseg * KC + B_DIM * KC) * 4ul > ws_size)
        nseg >>= 1;
    const int lrows = L_DIM / nseg;

    float* psum = ws;
    float* pcnt = ws + (long)B_DIM * nseg * KC;
    float* mean = ws + 2l * B_DIM * nseg * KC;

    // 1) private partial sums/counts, forced deep-MLP load ring
    partial_k<<<B_DIM * nseg, PT, 0, stream>>>(x, mask, psum, pcnt,
                                               nseg, lrows);

    // 2) fold partials, finalize mean
    mean_k<<<(B_DIM * KC) / 256, 256, 0, stream>>>(psum, pcnt, mean, nseg);

    // 3) broadcast to [B, L, K, C]
    bcast_k<<<B_DIM * (L_DIM / LCB), PT, 0, stream>>>(mean, out);
}

// Round 7
// 189.825 us; speedup vs baseline: 1.1732x; 1.1447x over previous
//
#include <hip/hip_runtime.h>

// Problem dims (fixed by reference): B=8, L=4096, K=32, C=64, KC=2048
#define B_DIM 8
#define L_DIM 4096
#define KC 2048              // K*C, contiguous innermost span per (b,l)
#define LCB  16              // l-rows per bcast block -> 2048 blocks
#define PT   512             // threads: one float4 column each

typedef float f4 __attribute__((ext_vector_type(4)));
typedef int   i4 __attribute__((ext_vector_type(4)));

// ---------------------------------------------------------------------------
// Stage 1: per-(b,segment) private partial sums/counts. No atomics.
// R3 structure (measured 155 us, equal to the forced asm ring of R5 -> the
// kernel is HBM-coupled, not latency-bound; keep the simple form).
// x is a zero-reuse stream: nontemporal loads keep it from evicting the
// L3-resident mask / absorbed out lines.
// ---------------------------------------------------------------------------
__global__ __launch_bounds__(PT) void partial_k(const float* __restrict__ x,
                                                const int* __restrict__ mask,
                                                float* __restrict__ psum,
                                                float* __restrict__ pcnt,
                                                int nseg, int lrows) {
    const int b   = blockIdx.x / nseg;
    const int seg = blockIdx.x % nseg;
    const int t   = threadIdx.x;

    const long base = ((long)b * L_DIM + (long)seg * lrows) * KC + t * 4;

    f4 s = {0.f, 0.f, 0.f, 0.f};
    f4 c = {0.f, 0.f, 0.f, 0.f};

    #pragma unroll 4
    for (int l = 0; l < lrows; ++l) {
        const f4 xv = __builtin_nontemporal_load(
                          (const f4*)(x + base + (long)l * KC));
        const i4 mv = *(const i4*)(mask + base + (long)l * KC);
        float m0 = (float)mv.x, m1 = (float)mv.y, m2 = (float)mv.z, m3 = (float)mv.w;
        s.x = fmaf(xv.x, m0, s.x);  c.x += m0;
        s.y = fmaf(xv.y, m1, s.y);  c.y += m1;
        s.z = fmaf(xv.z, m2, s.z);  c.z += m2;
        s.w = fmaf(xv.w, m3, s.w);  c.w += m3;
    }

    const long po = ((long)b * nseg + seg) * KC + t * 4;
    *(f4*)(&psum[po]) = s;
    *(f4*)(&pcnt[po]) = c;
}

// ---------------------------------------------------------------------------
// Stage 2: fold nseg partials per (b,j), finalize mean. B*KC = 16384 threads.
// ---------------------------------------------------------------------------
__global__ __launch_bounds__(256) void mean_k(const float* __restrict__ psum,
                                              const float* __restrict__ pcnt,
                                              float* __restrict__ mean,
                                              int nseg) {
    const int i = blockIdx.x * 256 + threadIdx.x;   // 0 .. B*KC-1
    const int b = i / KC;
    const int j = i % KC;

    float s = 0.f, c = 0.f;
    #pragma unroll 4
    for (int seg = 0; seg < nseg; ++seg) {
        const long o = ((long)b * nseg + seg) * KC + j;
        s += psum[o];
        c += pcnt[o];
    }
    mean[i] = (c > 0.f) ? (s / c) : 0.f;
}

// ---------------------------------------------------------------------------
// Stage 3: broadcast mean[b,:,:] to all L rows. mean is 64 KB -> L2-resident.
// Normal (cacheable) stores: L3 absorption of out re-writes between replays
// is measured profit — do NOT make these nontemporal.
// ---------------------------------------------------------------------------
__global__ __launch_bounds__(PT) void bcast_k(const float* __restrict__ mean,
                                              float* __restrict__ out) {
    const int blocks_per_b = L_DIM / LCB;           // 256
    const int b    = blockIdx.x / blocks_per_b;
    const int lseg = blockIdx.x % blocks_per_b;
    const int t    = threadIdx.x;

    const f4 v = *(const f4*)(&mean[(long)b * KC + t * 4]);

    const long base = ((long)b * L_DIM + (long)lseg * LCB) * KC + t * 4;
    #pragma unroll
    for (int l = 0; l < LCB; ++l)
        *(f4*)(out + base + (long)l * KC) = v;
}

extern "C" void kernel_launch(void* const* d_in, const int* in_sizes, int n_in,
                              void* d_out, int out_size, void* d_ws, size_t ws_size,
                              hipStream_t stream) {
    const float* x    = (const float*)d_in[0];
    const int*   mask = (const int*)d_in[1];
    float*       out  = (float*)d_out;
    float*       ws   = (float*)d_ws;

    // nseg=128 (R3 best): partials = 16.8 MB, lrows = 32.
    int nseg = 128;
    while (nseg > 8 &&
           (size_t)(2ul * B_DIM * nseg * KC + B_DIM * KC) * 4ul > ws_size)
        nseg >>= 1;
    const int lrows = L_DIM / nseg;

    float* psum = ws;
    float* pcnt = ws + (long)B_DIM * nseg * KC;
    float* mean = ws + 2l * B_DIM * nseg * KC;

    // 1) private partial sums/counts (no atomics)
    partial_k<<<B_DIM * nseg, PT, 0, stream>>>(x, mask, psum, pcnt,
                                               nseg, lrows);

    // 2) fold partials, finalize mean
    mean_k<<<(B_DIM * KC) / 256, 256, 0, stream>>>(psum, pcnt, mean, nseg);

    // 3) broadcast to [B, L, K, C]
    bcast_k<<<B_DIM * (L_DIM / LCB), PT, 0, stream>>>(mean, out);
}